// Round 4
// baseline (466.776 us; speedup 1.0000x reference)
//
#include <hip/hip_runtime.h>
#include <float.h>

// SearchTransfer MI355X — R14. k_mfma: B operand moved OFF the lds-DMA path.
// Evidence: wall/chunk == DMA time at ~10 B/cyc/CU (R10/R11/R12 triangulated)
// while data is L2-resident (FETCH 29MB vs 830MB staged) and regular loads
// sustain ~60 B/cyc/CU from L2 (m56). So the global_load_lds engine rate is
// the binding constraint -> halve its bytes: A stays DMA'd (32KB/chunk/CU,
// hides under 3725-cyc MFMA floor), B fragments loaded directly global->VGPR
// (global granule quad / 4+quad per row; the LDS XOR-swizzle decoded away).
// B loads issued BEFORE the A-prefetch each chunk + one sched_barrier(0) so
// the compiler's bf wait is vmcnt(2) and never drains in-flight A-DMA.
// Sync skeleton = R10 verbatim. LDS 128->64KB. k_pack2/k_foldmerge = R13.
// Split-f16 3-term GEMM (K'=320), top-2 guard tau=2^-6, pruned exact fixup.
// B=2, C=16, H=W=96, k=3,pad=1,stride=1, lv=2. L=9216, KF=144.
// out = [T_org (2*16*192*192 f32), S (2*9216 as f32)]

#define BATCH 2
#define CCH   16
#define HH    96
#define WW    96
#define LP    9216
#define KF    144
#define K3    320      // 5 chunks x 64 k' ; chunk = [hi32|lo32] of k-slice
#define OH    192
#define OW    192
#define NRT2  36       // row tiles of 256
#define NCB2  36       // col blocks of 256

typedef _Float16 f16;
typedef __attribute__((ext_vector_type(8))) _Float16 f16x8;
typedef __attribute__((ext_vector_type(4))) float    f32x4;

__device__ __forceinline__ void async16(const void* g, void* l) {
    __builtin_amdgcn_global_load_lds(
        (const __attribute__((address_space(1))) void*)g,
        (__attribute__((address_space(3))) void*)l, 16, 0, 0);
}

// ---------------------------------------------------- fused norm + pack ----
// UNCHANGED. Block = (py, batch, side*4+quarter). Norms bit-identical
// (zero-padded terms exact); writes 24 rows x 40 granules, layout:
// granule g: slice=g>>3, half=(g>>2)&1, j=g&3.
__global__ __launch_bounds__(256) void k_pack2(
        const float* __restrict__ ref, const float* __restrict__ lr,
        float* __restrict__ rinv, float* __restrict__ bns,
        f16* __restrict__ Abig, f16* __restrict__ Bbig) {
    __shared__ float imgS[CCH][3][26];   // x origin at global xi = q*24-1
    __shared__ float scl[24];
    int py = blockIdx.x, b = blockIdx.y;
    int side = blockIdx.z >> 2, q = blockIdx.z & 3;
    int tid = threadIdx.x;
    const float* img = (side ? lr : ref) + (size_t)b * CCH * HH * WW;

    for (int i = tid; i < CCH * 3 * 26; i += 256) {
        int c = i / 78, rem = i - c * 78;
        int rr = rem / 26, xx = rem - rr * 26;
        int y = py + rr - 1, xi = q * 24 - 1 + xx;
        float v = 0.f;
        if ((unsigned)y < (unsigned)HH && (unsigned)xi < (unsigned)WW)
            v = img[(c * HH + y) * WW + xi];
        imgS[c][rr][xx] = v;
    }
    __syncthreads();

    if (tid < 24) {
        int pxl = tid;
        float s = 0.f;
        for (int c = 0; c < CCH; ++c)
            #pragma unroll
            for (int dy = 0; dy < 3; ++dy)
                #pragma unroll
                for (int dx = 0; dx < 3; ++dx) {
                    float v = imgS[c][dy][pxl + dx];   // 0 when OOB: exact
                    s += v * v;
                }
        int gl = b * LP + py * 96 + q * 24 + pxl;
        if (side) { bns[gl] = 1024.0f * sqrtf(s); scl[pxl] = 1024.0f; }
        else { float r = 1.0f / fmaxf(sqrtf(s), 1e-12f); rinv[gl] = r; scl[pxl] = 1024.0f * r; }
    }
    __syncthreads();

    f16* dstb = (side ? Bbig : Abig) + (size_t)(b * LP + py * 96 + q * 24) * K3;
    for (int i = tid; i < 24 * 40; i += 256) {          // 40 granules/row
        int pxl = i / 40, g = i - pxl * 40;
        int chunk = g >> 3, half = (g >> 2) & 1, j = g & 3;
        int f0 = chunk * 32 + j * 8;                    // original k base
        float sc = scl[pxl];
        f16x8 o;
        #pragma unroll
        for (int e = 0; e < 8; ++e) {
            int f = f0 + e;                             // 0..159 (>=144 pad)
            float v = 0.f;
            if (f < KF) {
                int c = f / 9, r9 = f - c * 9;
                int dy = r9 / 3, dx = r9 - dy * 3;
                v = imgS[c][dy][pxl + dx] * sc;
            }
            f16 h = (f16)v;
            o[e] = half ? (f16)(v - (float)h) : h;
        }
        *(f16x8*)(dstb + (size_t)pxl * K3 + g * 8) = o;
    }
}

// -------------------------------------------------- MFMA GEMM + top-2 ------
// R14: A via global_load_lds double-buffer (32KB/chunk), B direct from
// global (L2) into VGPRs. Per chunk, program order: [8 B-loads]
// [sched_barrier(0)] [2 A-DMA prefetch] [A ds_reads + 48 MFMA]. The
// compiler's wait for bf is then vmcnt(2) (B issued before A-DMA), so the
// prefetch stays in flight across the whole chunk; chunk-top __syncthreads
// drains it exactly when needed. Global B granule layout (from pack2):
// chunk row = 128 B at ch*128; hi granules 0-3, lo granules 4-7; frag for
// (quad,l15) = row (wn*64+t*16+l15), granule quad (hi) / 4+quad (lo).
__global__ __launch_bounds__(1024) void k_mfma(
        const f16* __restrict__ Abig, const f16* __restrict__ Bbig,
        float* __restrict__ pv1, int* __restrict__ pi1, float* __restrict__ pv2) {
    __shared__ f16 smem[2][256 * 64];                  // 64 KB; A rows only
    int tid = threadIdx.x, lane = tid & 63, w = tid >> 6;   // w: 0..15
    int wm = w & 3, wn = w >> 2;
    int l15 = lane & 15, quad = lane >> 4, l7 = lane & 7;

    int i = blockIdx.x;                // 0..2591
    int xcd = i & 7, slot = i >> 3;    // slot 0..323
    int cb = slot / 9;                 // col tile 0..35 (major)
    int brt = xcd * 9 + (slot - cb * 9);   // 0..71
    int b = brt / NRT2, rt = brt - b * NRT2;
    int r0 = rt * 256, c0 = cb * 256;

    int srow = lane >> 3;              // row within group
    int sg   = (lane & 7) ^ srow;      // source granule (self-inverse swizzle)
    const f16* gsrc[2];
    int ldsbyte[2];                    // wave-uniform byte offset in one buffer
    #pragma unroll
    for (int j = 0; j < 2; ++j) {
        int G = w * 2 + j;             // 0..31
        int row8 = G * 8 + srow;       // 0..255 (A rows)
        gsrc[j] = Abig + (size_t)(b * LP + r0 + row8) * K3 + sg * 8;
        ldsbyte[j] = G * 1024;         // G*8 rows * 128 B/row
    }
    int arow[4];                       // A frag row byte offsets (stride 128 B)
    const f16* bp[4];                  // B frag global base (hi granule quad)
    #pragma unroll
    for (int t = 0; t < 4; ++t) {
        arow[t] = (wm * 64 + t * 16 + l15) * 128;
        bp[t] = Bbig + (size_t)(b * LP + c0 + wn * 64 + t * 16 + l15) * K3 + quad * 8;
    }
    int ph0 = ((quad) ^ l7) << 4;          // A ks=0 granules: hi slice
    int ph1 = ((4 + quad) ^ l7) << 4;      // A ks=1 granules: lo slice

    f32x4 acc[4][4];
    #pragma unroll
    for (int ii = 0; ii < 4; ++ii)
        #pragma unroll
        for (int j = 0; j < 4; ++j) { acc[ii][j][0]=0.f; acc[ii][j][1]=0.f; acc[ii][j][2]=0.f; acc[ii][j][3]=0.f; }

    // prologue: A chunk 0 -> buf 0
    #pragma unroll
    for (int j = 0; j < 2; ++j) async16(gsrc[j], (char*)smem[0] + ldsbyte[j]);

    for (int ch = 0; ch < 5; ++ch) {
        __syncthreads();               // drains A-DMA(ch); buf[ch&1] ready
        // B fragments for chunk ch: direct global (L2) -> VGPR, issued FIRST
        f16x8 bf0[4], bf1[4];
        #pragma unroll
        for (int t = 0; t < 4; ++t) bf0[t] = *(const f16x8*)(bp[t] + ch * 64);
        #pragma unroll
        for (int t = 0; t < 4; ++t) bf1[t] = *(const f16x8*)(bp[t] + ch * 64 + 32);
        __builtin_amdgcn_sched_barrier(0);   // pin: B issue precedes A-DMA issue
        if (ch < 4) {
            #pragma unroll
            for (int j = 0; j < 2; ++j)
                async16(gsrc[j] + (ch + 1) * 64, (char*)smem[(ch + 1) & 1] + ldsbyte[j]);
        }
        const char* buf = (const char*)smem[ch & 1];
        f16x8 af0[4], af1[4];
        // phase 1: hi*hi
        #pragma unroll
        for (int t = 0; t < 4; ++t) af0[t] = *(const f16x8*)(buf + arow[t] + ph0);
        #pragma unroll
        for (int rtt = 0; rtt < 4; ++rtt)
            #pragma unroll
            for (int ct = 0; ct < 4; ++ct)
                acc[rtt][ct] = __builtin_amdgcn_mfma_f32_16x16x32_f16(af0[rtt], bf0[ct], acc[rtt][ct], 0, 0, 0);
        // phase 2: hi*lo
        #pragma unroll
        for (int rtt = 0; rtt < 4; ++rtt)
            #pragma unroll
            for (int ct = 0; ct < 4; ++ct)
                acc[rtt][ct] = __builtin_amdgcn_mfma_f32_16x16x32_f16(af0[rtt], bf1[ct], acc[rtt][ct], 0, 0, 0);
        // phase 3: lo*hi
        #pragma unroll
        for (int t = 0; t < 4; ++t) af1[t] = *(const f16x8*)(buf + arow[t] + ph1);
        #pragma unroll
        for (int rtt = 0; rtt < 4; ++rtt)
            #pragma unroll
            for (int ct = 0; ct < 4; ++ct)
                acc[rtt][ct] = __builtin_amdgcn_mfma_f32_16x16x32_f16(af1[rtt], bf0[ct], acc[rtt][ct], 0, 0, 0);
    }
    __syncthreads();                   // smem reads done -> overlay epilogue scratch

    float* sv1 = (float*)smem;                         // [4][256]
    int*   si1 = (int*)  ((char*)smem + 4096);
    float* sv2 = (float*)((char*)smem + 8192);

    int rbase = r0 + wm * 64 + (quad << 2);
    #pragma unroll
    for (int ct = 0; ct < 4; ++ct) {
        float v1 = -FLT_MAX, v2 = -FLT_MAX; int i1 = 0;
        #pragma unroll
        for (int rtt = 0; rtt < 4; ++rtt)
            #pragma unroll
            for (int e = 0; e < 4; ++e) {              // ascending rows; strict > = first wins
                float v = acc[rtt][ct][e];
                int rg = rbase + rtt * 16 + e;
                if (v > v1) { v2 = v1; v1 = v; i1 = rg; }
                else if (v > v2) v2 = v;
            }
        #pragma unroll
        for (int off = 16; off < 64; off <<= 1) {      // reduce over quad (rows)
            float ov1 = __shfl_xor(v1, off, 64);
            int   oi1 = __shfl_xor(i1, off, 64);
            float ov2 = __shfl_xor(v2, off, 64);
            if (ov1 > v1 || (ov1 == v1 && oi1 < i1)) { v2 = fmaxf(v1, ov2); v1 = ov1; i1 = oi1; }
            else v2 = fmaxf(v2, ov1);
        }
        if (quad == 0) {
            int col = wn * 64 + ct * 16 + l15;
            sv1[wm * 256 + col] = v1; si1[wm * 256 + col] = i1; sv2[wm * 256 + col] = v2;
        }
    }
    __syncthreads();
    if (tid < 256) {
        int col = tid;
        float v1 = sv1[col]; int i1 = si1[col]; float v2 = sv2[col];
        #pragma unroll
        for (int m = 1; m < 4; ++m) {                  // ascending wm = ascending rows
            float ov1 = sv1[m * 256 + col]; int oi1 = si1[m * 256 + col]; float ov2 = sv2[m * 256 + col];
            if (ov1 > v1) { v2 = fmaxf(v1, ov2); v1 = ov1; i1 = oi1; }
            else v2 = fmaxf(v2, ov1);
        }
        size_t o = ((size_t)(b * NRT2 + rt)) * LP + c0 + col;
        pv1[o] = v1; pi1[o] = i1; pv2[o] = v2;
    }
}

// -------------------------------------- fused merge + fixup + fold ---------
// UNCHANGED from R13. 8x8 pixel tiles -> dim3(24,24,2)=1152 blocks.
// Phase A1: 216-thread partial merges (6 rc each, ascending). Phase A2:
// 36-thread final merge (ascending r), flag iff gap < tau, owner (4x4
// center) writes Sout. Phase B: exact pruned fixup (<=4-block dup,
// idempotent). Phase C: wave w = channels 4w..4w+3, lane = pixel.
__global__ __launch_bounds__(256) void k_foldmerge(
        const float* __restrict__ refimg, const float* __restrict__ lrimg,
        const float* __restrict__ rinv,
        const float* __restrict__ pv1, const int* __restrict__ pi1,
        const float* __restrict__ pv2, const float* __restrict__ bns,
        const float* __restrict__ org,
        float* __restrict__ outT, float* __restrict__ Sout) {
    __shared__ int   s_S[6][6];
    __shared__ int   s_flag[36];
    __shared__ int   s_nflag;
    __shared__ float pa_v1[36][6];
    __shared__ int   pa_i1[36][6];
    __shared__ float pa_v2[36][6];
    __shared__ float bcol[KF];
    __shared__ float spv[NRT2];
    __shared__ float red[4]; __shared__ int redi[4];
    int tx = blockIdx.x, ty = blockIdx.y, b = blockIdx.z;
    int x0 = tx * 8, y0 = ty * 8;
    int lhb = 4 * ty - 1; if (lhb < 0) lhb = 0;
    int lwb = 4 * tx - 1; if (lwb < 0) lwb = 0;
    int lhe = 4 * ty + 4; if (lhe > 95) lhe = 95;
    int lwe = 4 * tx + 4; if (lwe > 95) lwe = 95;
    int tid = threadIdx.x;

    if (tid == 0) s_nflag = 0;

    // ---- Phase A1: partial merges (patch p = tid/6, rc in [6r, 6r+6)) ----
    if (tid < 216) {
        int p = tid / 6, r = tid - p * 6;
        int ph = p / 6, pw = p - ph * 6;
        int lh = lhb + ph, lw = lwb + pw;
        if (lh <= lhe && lw <= lwe) {
            int col = lh * 96 + lw;
            float v1 = -FLT_MAX, v2 = -FLT_MAX; int i1 = 0;
            #pragma unroll
            for (int k = 0; k < 6; ++k) {              // ascending rc: first-wins
                int rc = r * 6 + k;
                size_t o = ((size_t)(b * NRT2 + rc)) * LP + col;
                float cv1 = pv1[o]; int ci1 = pi1[o]; float cv2 = pv2[o];
                if (cv1 > v1) { v2 = fmaxf(v1, cv2); v1 = cv1; i1 = ci1; }
                else v2 = fmaxf(v2, cv1);
            }
            pa_v1[p][r] = v1; pa_i1[p][r] = i1; pa_v2[p][r] = v2;
        }
    }
    __syncthreads();

    // ---- Phase A2: final merge over partials (ascending r = ascending rc) ----
    if (tid < 36) {
        int ph = tid / 6, pw = tid - ph * 6;
        int lh = lhb + ph, lw = lwb + pw;
        if (lh <= lhe && lw <= lwe) {
            int col = lh * 96 + lw;
            float v1 = pa_v1[tid][0]; int i1 = pa_i1[tid][0]; float v2 = pa_v2[tid][0];
            #pragma unroll
            for (int r = 1; r < 6; ++r) {              // later partials win on strict >
                float ov1 = pa_v1[tid][r]; int oi1 = pa_i1[tid][r]; float ov2 = pa_v2[tid][r];
                if (ov1 > v1) { v2 = fmaxf(v1, ov2); v1 = ov1; i1 = oi1; }
                else v2 = fmaxf(v2, ov1);
            }
            s_S[ph][pw] = i1;
            float tau = bns[b * LP + col] * 0.015625f; // 2^-6
            if (v1 - v2 < tau) { int k = atomicAdd(&s_nflag, 1); s_flag[k] = tid; }
            if (lh >= 4 * ty && lh < 4 * ty + 4 && lw >= 4 * tx && lw < 4 * tx + 4)
                Sout[b * LP + col] = (float)i1;        // owner write (partition)
        }
    }
    __syncthreads();

    // ---- Phase B: exact fixup for flagged patches (rare) ----
    int nf = s_nflag;
    for (int fi = 0; fi < nf; ++fi) {
        int pt = s_flag[fi];
        int ph = pt / 6, pw = pt - ph * 6;
        int lh = lhb + ph, lw = lwb + pw;
        int col = lh * 96 + lw, gid = b * LP + col;
        __syncthreads();                               // protect bcol/spv reuse
        if (tid < KF) {
            int c = tid / 9, r = tid - c * 9;
            int dy = r / 3, dx = r - dy * 3;
            int y = lh + dy - 1, x = lw + dx - 1;
            float v = 0.f;
            if ((unsigned)y < (unsigned)HH && (unsigned)x < (unsigned)WW)
                v = lrimg[((size_t)(b * CCH + c) * HH + y) * WW + x];
            bcol[tid] = v;
        }
        if (tid < NRT2) spv[tid] = pv1[((size_t)(b * NRT2 + tid)) * LP + col];
        __syncthreads();
        float v1 = -FLT_MAX;
        for (int rc = 0; rc < NRT2; ++rc) v1 = fmaxf(v1, spv[rc]);
        float thresh = v1 - bns[gid] * 0.015625f;
        float best = -FLT_MAX; int bi = 0x7fffffff;
        for (int rc = 0; rc < NRT2; ++rc) {            // ascending rows
            if (spv[rc] < thresh) continue;            // prune (uniform)
            int row = rc * 256 + tid;
            int py = row / WW, px = row - py * WW;
            float s = 0.f;
            for (int c = 0; c < CCH; ++c) {
                const float* ic = refimg + (size_t)(b * CCH + c) * HH * WW;
                #pragma unroll
                for (int dy = 0; dy < 3; ++dy) {
                    int y = py + dy - 1;
                    if ((unsigned)y >= (unsigned)HH) continue;
                    #pragma unroll
                    for (int dx = 0; dx < 3; ++dx) {
                        int x = px + dx - 1;
                        if ((unsigned)x >= (unsigned)WW) continue;
                        s = fmaf(ic[y * WW + x], bcol[c * 9 + dy * 3 + dx], s);
                    }
                }
            }
            s *= rinv[b * LP + row];
            if (s > best || (s == best && row < bi)) { best = s; bi = row; }
        }
        #pragma unroll
        for (int off = 1; off < 64; off <<= 1) {
            float ov = __shfl_xor(best, off, 64);
            int   oi = __shfl_xor(bi, off, 64);
            if (ov > best || (ov == best && oi < bi)) { best = ov; bi = oi; }
        }
        if ((tid & 63) == 0) { red[tid >> 6] = best; redi[tid >> 6] = bi; }
        __syncthreads();
        if (tid == 0) {
            float b0 = red[0]; int i0 = redi[0];
            for (int k = 1; k < 4; ++k)
                if (red[k] > b0 || (red[k] == b0 && redi[k] < i0)) { b0 = red[k]; i0 = redi[k]; }
            s_S[ph][pw] = i0;
            if (lh >= 4 * ty && lh < 4 * ty + 4 && lw >= 4 * tx && lw < 4 * tx + 4)
                Sout[gid] = (float)i0;
        }
    }
    __syncthreads();

    // ---- Phase C: fold; wave w = channels 4w..4w+3, lane = pixel ----
    int wid = tid >> 6, pix = tid & 63;
    int pyL = pix >> 3, pxL = pix & 7;
    int y = y0 + pyL, x = x0 + pxL;
    const float* orgb = org + ((size_t)b * CCH + wid * 4) * OH * OW;
    float acc[4];
    #pragma unroll
    for (int c = 0; c < 4; ++c) acc[c] = 0.f;
    int lhm = (y + 2) >> 1;
    int lwm = (x + 2) >> 1;
    int lh0 = lhm - 2 > 0 ? lhm - 2 : 0;
    int lh1 = lhm < 95 ? lhm : 95;
    int lw0 = lwm - 2 > 0 ? lwm - 2 : 0;
    int lw1 = lwm < 95 ? lwm : 95;
    for (int lh = lh0; lh <= lh1; ++lh) {
        int dy = y + 2 - 2 * lh;
        if (dy > 5) continue;
        for (int lw = lw0; lw <= lw1; ++lw) {
            int dx = x + 2 - 2 * lw;
            if (dx > 5) continue;
            int s  = s_S[lh - lhb][lw - lwb];
            int sh = s / 96, sw = s - sh * 96;
            int u = 2 * sh + dy - 2;
            int v = 2 * sw + dx - 2;
            if ((unsigned)u < (unsigned)OH && (unsigned)v < (unsigned)OW) {
                const float* p = orgb + u * OW + v;
                #pragma unroll
                for (int c = 0; c < 4; ++c) acc[c] += p[(size_t)c * OH * OW];
            }
        }
    }
    #pragma unroll
    for (int c = 0; c < 4; ++c)
        outT[(((size_t)(b * CCH + wid * 4 + c)) * OH + y) * OW + x] = acc[c];
}

// --------------------------------------------------------------- launch ----
extern "C" void kernel_launch(void* const* d_in, const int* in_sizes, int n_in,
                              void* d_out, int out_size, void* d_ws, size_t ws_size,
                              hipStream_t stream) {
    const float* lrsr  = (const float*)d_in[0];
    const float* refsr = (const float*)d_in[1];
    const float* org   = (const float*)d_in[2];

    char* ws = (char*)d_ws;
    size_t o = 0;
    float* rinv     = (float*)(ws + o); o += (size_t)BATCH * LP * 4;
    float* bns      = (float*)(ws + o); o += (size_t)BATCH * LP * 4;
    float* pv1      = (float*)(ws + o); o += (size_t)BATCH * NRT2 * LP * 4;
    int*   pi1      = (int*)  (ws + o); o += (size_t)BATCH * NRT2 * LP * 4;
    float* pv2      = (float*)(ws + o); o += (size_t)BATCH * NRT2 * LP * 4;
    f16*   Abig     = (f16*)  (ws + o); o += (size_t)BATCH * LP * K3 * 2;
    f16*   Bbig     = (f16*)  (ws + o); o += (size_t)BATCH * LP * K3 * 2;

    float* outT = (float*)d_out;                          // 2*16*192*192
    float* outS = outT + (size_t)BATCH * CCH * OH * OW;   // 2*9216 as f32

    k_pack2<<<dim3(96, BATCH, 8), 256, 0, stream>>>(refsr, lrsr, rinv, bns, Abig, Bbig);
    k_mfma<<<dim3(NCB2 * NRT2 * BATCH), 1024, 0, stream>>>(Abig, Bbig, pv1, pi1, pv2);
    k_foldmerge<<<dim3(24, 24, BATCH), 256, 0, stream>>>(refsr, lrsr, rinv, pv1, pi1, pv2, bns,
                                                         org, outT, outS);
}

// Round 5
// 442.331 us; speedup vs baseline: 1.0553x; 1.0553x over previous
//
#include <hip/hip_runtime.h>
#include <float.h>

// SearchTransfer MI355X — R15: single-term f16 GEMM (hi*hi only) + widened
// guard tau' = 0.5*bns (13 sigma vs measured-model error std 0.038*bns on
// the top-2 gap) + unchanged exact-fp32 fixup. Rationale: R10-R14
// triangulated k_mfma's wall = global_load_lds instruction rate (~125
// cyc/1KB-instr at 1 block/CU, fully overlapped already); only lever left
// is FEWER DMA instructions. K' 320->160: staged bytes 830->415 MB, DMA
// instrs/chunk 64->32, MFMA/chunk 48->16. Screening scores are now f16-
// rounded (err std 0.027*bns); any patch whose approx top-2 gap < tau' is
// re-argmaxed exactly in fp32 (flag rate ~2%/patch on random data), so
// output indices stay exact. LDS: rows are 64-B slices, 2 rows per 128-B
// line, granule XOR swizzle (q ^ (line&3)) baked into the per-lane DMA
// source address; ds_read_b128 start-banks uniform 8/bank-group (same
// conflict-free pattern as the proven 128-B-row layout).
// k_mfma sync skeleton = R10 verbatim (proven optimum).
// B=2, C=16, H=W=96, k=3,pad=1,stride=1, lv=2. L=9216, KF=144.
// out = [T_org (2*16*192*192 f32), S (2*9216 as f32)]

#define BATCH 2
#define CCH   16
#define HH    96
#define WW    96
#define LP    9216
#define KF    144
#define K3    160      // 5 chunks x 32 k' (hi f16 only; k'>=144 zero-pad)
#define OH    192
#define OW    192
#define NRT2  36       // row tiles of 256
#define NCB2  36       // col blocks of 256

typedef _Float16 f16;
typedef __attribute__((ext_vector_type(8))) _Float16 f16x8;
typedef __attribute__((ext_vector_type(4))) float    f32x4;

__device__ __forceinline__ void async16(const void* g, void* l) {
    __builtin_amdgcn_global_load_lds(
        (const __attribute__((address_space(1))) void*)g,
        (__attribute__((address_space(3))) void*)l, 16, 0, 0);
}

// ---------------------------------------------------- fused norm + pack ----
// R15: hi f16 only (no residual). Norms still exact fp32 (zero-padded terms
// exact). Writes 24 rows x 20 granules; granule g = k' 8g..8g+7, f>=144 -> 0.
__global__ __launch_bounds__(256) void k_pack2(
        const float* __restrict__ ref, const float* __restrict__ lr,
        float* __restrict__ rinv, float* __restrict__ bns,
        f16* __restrict__ Abig, f16* __restrict__ Bbig) {
    __shared__ float imgS[CCH][3][26];   // x origin at global xi = q*24-1
    __shared__ float scl[24];
    int py = blockIdx.x, b = blockIdx.y;
    int side = blockIdx.z >> 2, q = blockIdx.z & 3;
    int tid = threadIdx.x;
    const float* img = (side ? lr : ref) + (size_t)b * CCH * HH * WW;

    for (int i = tid; i < CCH * 3 * 26; i += 256) {
        int c = i / 78, rem = i - c * 78;
        int rr = rem / 26, xx = rem - rr * 26;
        int y = py + rr - 1, xi = q * 24 - 1 + xx;
        float v = 0.f;
        if ((unsigned)y < (unsigned)HH && (unsigned)xi < (unsigned)WW)
            v = img[(c * HH + y) * WW + xi];
        imgS[c][rr][xx] = v;
    }
    __syncthreads();

    if (tid < 24) {
        int pxl = tid;
        float s = 0.f;
        for (int c = 0; c < CCH; ++c)
            #pragma unroll
            for (int dy = 0; dy < 3; ++dy)
                #pragma unroll
                for (int dx = 0; dx < 3; ++dx) {
                    float v = imgS[c][dy][pxl + dx];   // 0 when OOB: exact
                    s += v * v;
                }
        int gl = b * LP + py * 96 + q * 24 + pxl;
        if (side) { bns[gl] = 1024.0f * sqrtf(s); scl[pxl] = 1024.0f; }
        else { float r = 1.0f / fmaxf(sqrtf(s), 1e-12f); rinv[gl] = r; scl[pxl] = 1024.0f * r; }
    }
    __syncthreads();

    f16* dstb = (side ? Bbig : Abig) + (size_t)(b * LP + py * 96 + q * 24) * K3;
    for (int i = tid; i < 24 * 20; i += 256) {          // 20 granules/row
        int pxl = i / 20, g = i - pxl * 20;
        int f0 = g * 8;
        float sc = scl[pxl];
        f16x8 o;
        #pragma unroll
        for (int e = 0; e < 8; ++e) {
            int f = f0 + e;                             // 0..159 (>=144 pad)
            float v = 0.f;
            if (f < KF) {
                int c = f / 9, r9 = f - c * 9;
                int dy = r9 / 3, dx = r9 - dy * 3;
                v = imgS[c][dy][pxl + dx] * sc;
            }
            o[e] = (f16)v;
        }
        *(f16x8*)(dstb + (size_t)pxl * K3 + g * 8) = o;
    }
}

// -------------------------------------------------- MFMA GEMM + top-2 ------
// R15: single-term. Chunk = 32 k' (64 B/row). LDS buffer = 256 lines x
// 128 B (2 rows/line): row r at line r>>1, half (r&1), granule position
// p = q ^ ((r>>1)&3). DMA: 2 instrs/wave/chunk (32/block); per-lane source
// pre-swizzled so the linear LDS write lands the swizzled layout. Sync
// skeleton = R10 (single __syncthreads per chunk, depth-1 prefetch).
__global__ __launch_bounds__(1024) void k_mfma(
        const f16* __restrict__ Abig, const f16* __restrict__ Bbig,
        float* __restrict__ pv1, int* __restrict__ pi1, float* __restrict__ pv2) {
    __shared__ f16 smem[2][256 * 64];                  // 2 x 32 KB
    int tid = threadIdx.x, lane = tid & 63, w = tid >> 6;   // w: 0..15
    int wm = w & 3, wn = w >> 2;
    int l15 = lane & 15, quad = lane >> 4;

    int i = blockIdx.x;                // 0..2591
    int xcd = i & 7, slot = i >> 3;    // slot 0..323
    int cb = slot / 9;                 // col tile 0..35 (major)
    int brt = xcd * 9 + (slot - cb * 9);   // 0..71
    int b = brt / NRT2, rt = brt - b * NRT2;
    int r0 = rt * 256, c0 = cb * 256;

    // DMA source: group G = w*2+j covers rows [16G,16G+16) = 8 LDS lines.
    // lane -> line offset lane>>3, slot s=lane&7: row-in-group
    // ri = 2*(lane>>3) + ((lane>>2)&1), granule pos p = lane&3, source
    // granule q = p ^ (line&3) = (lane&3) ^ ((lane>>3)&3)  [16G = 0 mod 4].
    int ri  = ((lane >> 3) << 1) | ((lane >> 2) & 1);
    int qsw = (lane & 3) ^ ((lane >> 3) & 3);
    const f16* gsrc[2];
    int ldsbyte[2];                    // wave-uniform byte offset in one buffer
    #pragma unroll
    for (int j = 0; j < 2; ++j) {
        int G = w * 2 + j;             // 0..31
        int row8 = G * 16 + ri;        // 0..511 (A rows then B rows)
        const f16* base = (row8 < 256)
            ? Abig + (size_t)(b * LP + r0 + row8) * K3
            : Bbig + (size_t)(b * LP + c0 + (row8 - 256)) * K3;
        gsrc[j] = base + qsw * 8;
        ldsbyte[j] = G * 1024;         // 16 rows * 64 B
    }
    // ds_read byte offsets: row r -> line (r>>1), half (r&1), granule
    // position quad ^ ((r>>1)&3). With r = base + l15 (base = wm*64+t*16,
    // base>>1 = 0 mod 4): line = wm*32+t*8+(l15>>1), key = (l15>>1)&3.
    int l2 = l15 >> 1, lo1 = l15 & 1;
    int gsel = (quad ^ (l2 & 3)) * 16;
    int abyte[4], bbyte[4];
    #pragma unroll
    for (int t = 0; t < 4; ++t) {
        abyte[t] = (wm * 32 + t * 8 + l2) * 128 + lo1 * 64 + gsel;
        bbyte[t] = (128 + wn * 32 + t * 8 + l2) * 128 + lo1 * 64 + gsel;
    }

    f32x4 acc[4][4];
    #pragma unroll
    for (int ii = 0; ii < 4; ++ii)
        #pragma unroll
        for (int j = 0; j < 4; ++j) { acc[ii][j][0]=0.f; acc[ii][j][1]=0.f; acc[ii][j][2]=0.f; acc[ii][j][3]=0.f; }

    // prologue: chunk 0 -> buf 0
    #pragma unroll
    for (int j = 0; j < 2; ++j) async16(gsrc[j], (char*)smem[0] + ldsbyte[j]);

    for (int ch = 0; ch < 5; ++ch) {
        __syncthreads();               // drains own DMA; buf[ch&1] ready
        if (ch < 4) {
            #pragma unroll
            for (int j = 0; j < 2; ++j)
                async16(gsrc[j] + (ch + 1) * 32, (char*)smem[(ch + 1) & 1] + ldsbyte[j]);
        }
        const char* buf = (const char*)smem[ch & 1];
        f16x8 af[4], bf[4];
        #pragma unroll
        for (int t = 0; t < 4; ++t) af[t] = *(const f16x8*)(buf + abyte[t]);
        #pragma unroll
        for (int t = 0; t < 4; ++t) bf[t] = *(const f16x8*)(buf + bbyte[t]);
        #pragma unroll
        for (int rtt = 0; rtt < 4; ++rtt)
            #pragma unroll
            for (int ct = 0; ct < 4; ++ct)
                acc[rtt][ct] = __builtin_amdgcn_mfma_f32_16x16x32_f16(af[rtt], bf[ct], acc[rtt][ct], 0, 0, 0);
    }
    __syncthreads();                   // smem reads done -> overlay epilogue scratch

    float* sv1 = (float*)smem;                         // [4][256]
    int*   si1 = (int*)  ((char*)smem + 4096);
    float* sv2 = (float*)((char*)smem + 8192);

    int rbase = r0 + wm * 64 + (quad << 2);
    #pragma unroll
    for (int ct = 0; ct < 4; ++ct) {
        float v1 = -FLT_MAX, v2 = -FLT_MAX; int i1 = 0;
        #pragma unroll
        for (int rtt = 0; rtt < 4; ++rtt)
            #pragma unroll
            for (int e = 0; e < 4; ++e) {              // ascending rows; strict > = first wins
                float v = acc[rtt][ct][e];
                int rg = rbase + rtt * 16 + e;
                if (v > v1) { v2 = v1; v1 = v; i1 = rg; }
                else if (v > v2) v2 = v;
            }
        #pragma unroll
        for (int off = 16; off < 64; off <<= 1) {      // reduce over quad (rows)
            float ov1 = __shfl_xor(v1, off, 64);
            int   oi1 = __shfl_xor(i1, off, 64);
            float ov2 = __shfl_xor(v2, off, 64);
            if (ov1 > v1 || (ov1 == v1 && oi1 < i1)) { v2 = fmaxf(v1, ov2); v1 = ov1; i1 = oi1; }
            else v2 = fmaxf(v2, ov1);
        }
        if (quad == 0) {
            int col = wn * 64 + ct * 16 + l15;
            sv1[wm * 256 + col] = v1; si1[wm * 256 + col] = i1; sv2[wm * 256 + col] = v2;
        }
    }
    __syncthreads();
    if (tid < 256) {
        int col = tid;
        float v1 = sv1[col]; int i1 = si1[col]; float v2 = sv2[col];
        #pragma unroll
        for (int m = 1; m < 4; ++m) {                  // ascending wm = ascending rows
            float ov1 = sv1[m * 256 + col]; int oi1 = si1[m * 256 + col]; float ov2 = sv2[m * 256 + col];
            if (ov1 > v1) { v2 = fmaxf(v1, ov2); v1 = ov1; i1 = oi1; }
            else v2 = fmaxf(v2, ov1);
        }
        size_t o = ((size_t)(b * NRT2 + rt)) * LP + c0 + col;
        pv1[o] = v1; pi1[o] = i1; pv2[o] = v2;
    }
}

// -------------------------------------- fused merge + fixup + fold ---------
// R13 structure; tau widened to 0.5*bns for the single-term screen.
// Phase A1: 216-thread partial merges (6 rc each, ascending). Phase A2:
// 36-thread final merge (ascending r), flag iff gap < tau', owner (4x4
// center) writes Sout. Phase B: exact pruned fp32 fixup (<=4-block dup,
// idempotent; prune margin = same tau'). Phase C: wave w = channels
// 4w..4w+3, lane = pixel.
__global__ __launch_bounds__(256) void k_foldmerge(
        const float* __restrict__ refimg, const float* __restrict__ lrimg,
        const float* __restrict__ rinv,
        const float* __restrict__ pv1, const int* __restrict__ pi1,
        const float* __restrict__ pv2, const float* __restrict__ bns,
        const float* __restrict__ org,
        float* __restrict__ outT, float* __restrict__ Sout) {
    __shared__ int   s_S[6][6];
    __shared__ int   s_flag[36];
    __shared__ int   s_nflag;
    __shared__ float pa_v1[36][6];
    __shared__ int   pa_i1[36][6];
    __shared__ float pa_v2[36][6];
    __shared__ float bcol[KF];
    __shared__ float spv[NRT2];
    __shared__ float red[4]; __shared__ int redi[4];
    int tx = blockIdx.x, ty = blockIdx.y, b = blockIdx.z;
    int x0 = tx * 8, y0 = ty * 8;
    int lhb = 4 * ty - 1; if (lhb < 0) lhb = 0;
    int lwb = 4 * tx - 1; if (lwb < 0) lwb = 0;
    int lhe = 4 * ty + 4; if (lhe > 95) lhe = 95;
    int lwe = 4 * tx + 4; if (lwe > 95) lwe = 95;
    int tid = threadIdx.x;

    if (tid == 0) s_nflag = 0;

    // ---- Phase A1: partial merges (patch p = tid/6, rc in [6r, 6r+6)) ----
    if (tid < 216) {
        int p = tid / 6, r = tid - p * 6;
        int ph = p / 6, pw = p - ph * 6;
        int lh = lhb + ph, lw = lwb + pw;
        if (lh <= lhe && lw <= lwe) {
            int col = lh * 96 + lw;
            float v1 = -FLT_MAX, v2 = -FLT_MAX; int i1 = 0;
            #pragma unroll
            for (int k = 0; k < 6; ++k) {              // ascending rc: first-wins
                int rc = r * 6 + k;
                size_t o = ((size_t)(b * NRT2 + rc)) * LP + col;
                float cv1 = pv1[o]; int ci1 = pi1[o]; float cv2 = pv2[o];
                if (cv1 > v1) { v2 = fmaxf(v1, cv2); v1 = cv1; i1 = ci1; }
                else v2 = fmaxf(v2, cv1);
            }
            pa_v1[p][r] = v1; pa_i1[p][r] = i1; pa_v2[p][r] = v2;
        }
    }
    __syncthreads();

    // ---- Phase A2: final merge over partials (ascending r = ascending rc) ----
    if (tid < 36) {
        int ph = tid / 6, pw = tid - ph * 6;
        int lh = lhb + ph, lw = lwb + pw;
        if (lh <= lhe && lw <= lwe) {
            int col = lh * 96 + lw;
            float v1 = pa_v1[tid][0]; int i1 = pa_i1[tid][0]; float v2 = pa_v2[tid][0];
            #pragma unroll
            for (int r = 1; r < 6; ++r) {              // later partials win on strict >
                float ov1 = pa_v1[tid][r]; int oi1 = pa_i1[tid][r]; float ov2 = pa_v2[tid][r];
                if (ov1 > v1) { v2 = fmaxf(v1, ov2); v1 = ov1; i1 = oi1; }
                else v2 = fmaxf(v2, ov1);
            }
            s_S[ph][pw] = i1;
            float tau = bns[b * LP + col] * 0.5f;      // tau' = 0.5*bns (13 sigma)
            if (v1 - v2 < tau) { int k = atomicAdd(&s_nflag, 1); s_flag[k] = tid; }
            if (lh >= 4 * ty && lh < 4 * ty + 4 && lw >= 4 * tx && lw < 4 * tx + 4)
                Sout[b * LP + col] = (float)i1;        // owner write (partition)
        }
    }
    __syncthreads();

    // ---- Phase B: exact fixup for flagged patches (uncommon, ~2%/patch) ----
    int nf = s_nflag;
    for (int fi = 0; fi < nf; ++fi) {
        int pt = s_flag[fi];
        int ph = pt / 6, pw = pt - ph * 6;
        int lh = lhb + ph, lw = lwb + pw;
        int col = lh * 96 + lw, gid = b * LP + col;
        __syncthreads();                               // protect bcol/spv reuse
        if (tid < KF) {
            int c = tid / 9, r = tid - c * 9;
            int dy = r / 3, dx = r - dy * 3;
            int y = lh + dy - 1, x = lw + dx - 1;
            float v = 0.f;
            if ((unsigned)y < (unsigned)HH && (unsigned)x < (unsigned)WW)
                v = lrimg[((size_t)(b * CCH + c) * HH + y) * WW + x];
            bcol[tid] = v;
        }
        if (tid < NRT2) spv[tid] = pv1[((size_t)(b * NRT2 + tid)) * LP + col];
        __syncthreads();
        float v1 = -FLT_MAX;
        for (int rc = 0; rc < NRT2; ++rc) v1 = fmaxf(v1, spv[rc]);
        float thresh = v1 - bns[gid] * 0.5f;           // same tau' margin
        float best = -FLT_MAX; int bi = 0x7fffffff;
        for (int rc = 0; rc < NRT2; ++rc) {            // ascending rows
            if (spv[rc] < thresh) continue;            // prune (uniform)
            int row = rc * 256 + tid;
            int py = row / WW, px = row - py * WW;
            float s = 0.f;
            for (int c = 0; c < CCH; ++c) {
                const float* ic = refimg + (size_t)(b * CCH + c) * HH * WW;
                #pragma unroll
                for (int dy = 0; dy < 3; ++dy) {
                    int y = py + dy - 1;
                    if ((unsigned)y >= (unsigned)HH) continue;
                    #pragma unroll
                    for (int dx = 0; dx < 3; ++dx) {
                        int x = px + dx - 1;
                        if ((unsigned)x >= (unsigned)WW) continue;
                        s = fmaf(ic[y * WW + x], bcol[c * 9 + dy * 3 + dx], s);
                    }
                }
            }
            s *= rinv[b * LP + row];
            if (s > best || (s == best && row < bi)) { best = s; bi = row; }
        }
        #pragma unroll
        for (int off = 1; off < 64; off <<= 1) {
            float ov = __shfl_xor(best, off, 64);
            int   oi = __shfl_xor(bi, off, 64);
            if (ov > best || (ov == best && oi < bi)) { best = ov; bi = oi; }
        }
        if ((tid & 63) == 0) { red[tid >> 6] = best; redi[tid >> 6] = bi; }
        __syncthreads();
        if (tid == 0) {
            float b0 = red[0]; int i0 = redi[0];
            for (int k = 1; k < 4; ++k)
                if (red[k] > b0 || (red[k] == b0 && redi[k] < i0)) { b0 = red[k]; i0 = redi[k]; }
            s_S[ph][pw] = i0;
            if (lh >= 4 * ty && lh < 4 * ty + 4 && lw >= 4 * tx && lw < 4 * tx + 4)
                Sout[gid] = (float)i0;
        }
    }
    __syncthreads();

    // ---- Phase C: fold; wave w = channels 4w..4w+3, lane = pixel ----
    int wid = tid >> 6, pix = tid & 63;
    int pyL = pix >> 3, pxL = pix & 7;
    int y = y0 + pyL, x = x0 + pxL;
    const float* orgb = org + ((size_t)b * CCH + wid * 4) * OH * OW;
    float acc[4];
    #pragma unroll
    for (int c = 0; c < 4; ++c) acc[c] = 0.f;
    int lhm = (y + 2) >> 1;
    int lwm = (x + 2) >> 1;
    int lh0 = lhm - 2 > 0 ? lhm - 2 : 0;
    int lh1 = lhm < 95 ? lhm : 95;
    int lw0 = lwm - 2 > 0 ? lwm - 2 : 0;
    int lw1 = lwm < 95 ? lwm : 95;
    for (int lh = lh0; lh <= lh1; ++lh) {
        int dy = y + 2 - 2 * lh;
        if (dy > 5) continue;
        for (int lw = lw0; lw <= lw1; ++lw) {
            int dx = x + 2 - 2 * lw;
            if (dx > 5) continue;
            int s  = s_S[lh - lhb][lw - lwb];
            int sh = s / 96, sw = s - sh * 96;
            int u = 2 * sh + dy - 2;
            int v = 2 * sw + dx - 2;
            if ((unsigned)u < (unsigned)OH && (unsigned)v < (unsigned)OW) {
                const float* p = orgb + u * OW + v;
                #pragma unroll
                for (int c = 0; c < 4; ++c) acc[c] += p[(size_t)c * OH * OW];
            }
        }
    }
    #pragma unroll
    for (int c = 0; c < 4; ++c)
        outT[(((size_t)(b * CCH + wid * 4 + c)) * OH + y) * OW + x] = acc[c];
}

// --------------------------------------------------------------- launch ----
extern "C" void kernel_launch(void* const* d_in, const int* in_sizes, int n_in,
                              void* d_out, int out_size, void* d_ws, size_t ws_size,
                              hipStream_t stream) {
    const float* lrsr  = (const float*)d_in[0];
    const float* refsr = (const float*)d_in[1];
    const float* org   = (const float*)d_in[2];

    char* ws = (char*)d_ws;
    size_t o = 0;
    float* rinv     = (float*)(ws + o); o += (size_t)BATCH * LP * 4;
    float* bns      = (float*)(ws + o); o += (size_t)BATCH * LP * 4;
    float* pv1      = (float*)(ws + o); o += (size_t)BATCH * NRT2 * LP * 4;
    int*   pi1      = (int*)  (ws + o); o += (size_t)BATCH * NRT2 * LP * 4;
    float* pv2      = (float*)(ws + o); o += (size_t)BATCH * NRT2 * LP * 4;
    f16*   Abig     = (f16*)  (ws + o); o += (size_t)BATCH * LP * K3 * 2;
    f16*   Bbig     = (f16*)  (ws + o); o += (size_t)BATCH * LP * K3 * 2;

    float* outT = (float*)d_out;                          // 2*16*192*192
    float* outS = outT + (size_t)BATCH * CCH * OH * OW;   // 2*9216 as f32

    k_pack2<<<dim3(96, BATCH, 8), 256, 0, stream>>>(refsr, lrsr, rinv, bns, Abig, Bbig);
    k_mfma<<<dim3(NCB2 * NRT2 * BATCH), 1024, 0, stream>>>(Abig, Bbig, pv1, pi1, pv2);
    k_foldmerge<<<dim3(24, 24, BATCH), 256, 0, stream>>>(refsr, lrsr, rinv, pv1, pi1, pv2, bns,
                                                         org, outT, outS);
}

// Round 6
// 296.066 us; speedup vs baseline: 1.5766x; 1.4940x over previous
//
#include <hip/hip_runtime.h>
#include <float.h>

// SearchTransfer MI355X — R16. Keep R15's single-term GEMM (K'=160, guard
// tau'=0.5*bns validated: absmax unchanged with fix path heavily used).
// Fix the tail: R15's k_foldmerge hit 266us from (a) strided pv merge reads
// (FETCH 90MB, 30x overfetch, latency-bound) and (b) serialized+duplicated
// in-block fixups at the 32x-wider flag rate. Restructure into:
//   k_merge: col-parallel, rc-loop -> fully coalesced pv reads (each elem
//            read once), writes final S + compact global flag list.
//   k_fix:   grid-stride over flag list, one block per flagged col; exact
//            fp32 argmax (R15 Phase B verbatim), no duplication, balanced.
//   k_fold:  pure fold from final S.
// k_pack2 + k_mfma unchanged from R15.
// B=2, C=16, H=W=96, k=3,pad=1,stride=1, lv=2. L=9216, KF=144.
// out = [T_org (2*16*192*192 f32), S (2*9216 as f32)]

#define BATCH 2
#define CCH   16
#define HH    96
#define WW    96
#define LP    9216
#define KF    144
#define K3    160      // 5 chunks x 32 k' (hi f16 only; k'>=144 zero-pad)
#define OH    192
#define OW    192
#define NRT2  36       // row tiles of 256
#define NCB2  36       // col blocks of 256

typedef _Float16 f16;
typedef __attribute__((ext_vector_type(8))) _Float16 f16x8;
typedef __attribute__((ext_vector_type(4))) float    f32x4;

__device__ __forceinline__ void async16(const void* g, void* l) {
    __builtin_amdgcn_global_load_lds(
        (const __attribute__((address_space(1))) void*)g,
        (__attribute__((address_space(3))) void*)l, 16, 0, 0);
}

// ---------------------------------------------------- fused norm + pack ----
// UNCHANGED from R15. hi f16 only. Norms exact fp32.
__global__ __launch_bounds__(256) void k_pack2(
        const float* __restrict__ ref, const float* __restrict__ lr,
        float* __restrict__ rinv, float* __restrict__ bns,
        f16* __restrict__ Abig, f16* __restrict__ Bbig) {
    __shared__ float imgS[CCH][3][26];   // x origin at global xi = q*24-1
    __shared__ float scl[24];
    int py = blockIdx.x, b = blockIdx.y;
    int side = blockIdx.z >> 2, q = blockIdx.z & 3;
    int tid = threadIdx.x;
    const float* img = (side ? lr : ref) + (size_t)b * CCH * HH * WW;

    for (int i = tid; i < CCH * 3 * 26; i += 256) {
        int c = i / 78, rem = i - c * 78;
        int rr = rem / 26, xx = rem - rr * 26;
        int y = py + rr - 1, xi = q * 24 - 1 + xx;
        float v = 0.f;
        if ((unsigned)y < (unsigned)HH && (unsigned)xi < (unsigned)WW)
            v = img[(c * HH + y) * WW + xi];
        imgS[c][rr][xx] = v;
    }
    __syncthreads();

    if (tid < 24) {
        int pxl = tid;
        float s = 0.f;
        for (int c = 0; c < CCH; ++c)
            #pragma unroll
            for (int dy = 0; dy < 3; ++dy)
                #pragma unroll
                for (int dx = 0; dx < 3; ++dx) {
                    float v = imgS[c][dy][pxl + dx];   // 0 when OOB: exact
                    s += v * v;
                }
        int gl = b * LP + py * 96 + q * 24 + pxl;
        if (side) { bns[gl] = 1024.0f * sqrtf(s); scl[pxl] = 1024.0f; }
        else { float r = 1.0f / fmaxf(sqrtf(s), 1e-12f); rinv[gl] = r; scl[pxl] = 1024.0f * r; }
    }
    __syncthreads();

    f16* dstb = (side ? Bbig : Abig) + (size_t)(b * LP + py * 96 + q * 24) * K3;
    for (int i = tid; i < 24 * 20; i += 256) {          // 20 granules/row
        int pxl = i / 20, g = i - pxl * 20;
        int f0 = g * 8;
        float sc = scl[pxl];
        f16x8 o;
        #pragma unroll
        for (int e = 0; e < 8; ++e) {
            int f = f0 + e;                             // 0..159 (>=144 pad)
            float v = 0.f;
            if (f < KF) {
                int c = f / 9, r9 = f - c * 9;
                int dy = r9 / 3, dx = r9 - dy * 3;
                v = imgS[c][dy][pxl + dx] * sc;
            }
            o[e] = (f16)v;
        }
        *(f16x8*)(dstb + (size_t)pxl * K3 + g * 8) = o;
    }
}

// -------------------------------------------------- MFMA GEMM + top-2 ------
// UNCHANGED from R15. Single-term, chunk = 32 k' (64 B/row), R10 sync
// skeleton, pre-swizzled DMA source, conflict-free ds_read_b128 layout.
__global__ __launch_bounds__(1024) void k_mfma(
        const f16* __restrict__ Abig, const f16* __restrict__ Bbig,
        float* __restrict__ pv1, int* __restrict__ pi1, float* __restrict__ pv2) {
    __shared__ f16 smem[2][256 * 64];                  // 2 x 32 KB
    int tid = threadIdx.x, lane = tid & 63, w = tid >> 6;   // w: 0..15
    int wm = w & 3, wn = w >> 2;
    int l15 = lane & 15, quad = lane >> 4;

    int i = blockIdx.x;                // 0..2591
    int xcd = i & 7, slot = i >> 3;    // slot 0..323
    int cb = slot / 9;                 // col tile 0..35 (major)
    int brt = xcd * 9 + (slot - cb * 9);   // 0..71
    int b = brt / NRT2, rt = brt - b * NRT2;
    int r0 = rt * 256, c0 = cb * 256;

    int ri  = ((lane >> 3) << 1) | ((lane >> 2) & 1);
    int qsw = (lane & 3) ^ ((lane >> 3) & 3);
    const f16* gsrc[2];
    int ldsbyte[2];                    // wave-uniform byte offset in one buffer
    #pragma unroll
    for (int j = 0; j < 2; ++j) {
        int G = w * 2 + j;             // 0..31
        int row8 = G * 16 + ri;        // 0..511 (A rows then B rows)
        const f16* base = (row8 < 256)
            ? Abig + (size_t)(b * LP + r0 + row8) * K3
            : Bbig + (size_t)(b * LP + c0 + (row8 - 256)) * K3;
        gsrc[j] = base + qsw * 8;
        ldsbyte[j] = G * 1024;         // 16 rows * 64 B
    }
    int l2 = l15 >> 1, lo1 = l15 & 1;
    int gsel = (quad ^ (l2 & 3)) * 16;
    int abyte[4], bbyte[4];
    #pragma unroll
    for (int t = 0; t < 4; ++t) {
        abyte[t] = (wm * 32 + t * 8 + l2) * 128 + lo1 * 64 + gsel;
        bbyte[t] = (128 + wn * 32 + t * 8 + l2) * 128 + lo1 * 64 + gsel;
    }

    f32x4 acc[4][4];
    #pragma unroll
    for (int ii = 0; ii < 4; ++ii)
        #pragma unroll
        for (int j = 0; j < 4; ++j) { acc[ii][j][0]=0.f; acc[ii][j][1]=0.f; acc[ii][j][2]=0.f; acc[ii][j][3]=0.f; }

    // prologue: chunk 0 -> buf 0
    #pragma unroll
    for (int j = 0; j < 2; ++j) async16(gsrc[j], (char*)smem[0] + ldsbyte[j]);

    for (int ch = 0; ch < 5; ++ch) {
        __syncthreads();               // drains own DMA; buf[ch&1] ready
        if (ch < 4) {
            #pragma unroll
            for (int j = 0; j < 2; ++j)
                async16(gsrc[j] + (ch + 1) * 32, (char*)smem[(ch + 1) & 1] + ldsbyte[j]);
        }
        const char* buf = (const char*)smem[ch & 1];
        f16x8 af[4], bf[4];
        #pragma unroll
        for (int t = 0; t < 4; ++t) af[t] = *(const f16x8*)(buf + abyte[t]);
        #pragma unroll
        for (int t = 0; t < 4; ++t) bf[t] = *(const f16x8*)(buf + bbyte[t]);
        #pragma unroll
        for (int rtt = 0; rtt < 4; ++rtt)
            #pragma unroll
            for (int ct = 0; ct < 4; ++ct)
                acc[rtt][ct] = __builtin_amdgcn_mfma_f32_16x16x32_f16(af[rtt], bf[ct], acc[rtt][ct], 0, 0, 0);
    }
    __syncthreads();                   // smem reads done -> overlay epilogue scratch

    float* sv1 = (float*)smem;                         // [4][256]
    int*   si1 = (int*)  ((char*)smem + 4096);
    float* sv2 = (float*)((char*)smem + 8192);

    int rbase = r0 + wm * 64 + (quad << 2);
    #pragma unroll
    for (int ct = 0; ct < 4; ++ct) {
        float v1 = -FLT_MAX, v2 = -FLT_MAX; int i1 = 0;
        #pragma unroll
        for (int rtt = 0; rtt < 4; ++rtt)
            #pragma unroll
            for (int e = 0; e < 4; ++e) {              // ascending rows; strict > = first wins
                float v = acc[rtt][ct][e];
                int rg = rbase + rtt * 16 + e;
                if (v > v1) { v2 = v1; v1 = v; i1 = rg; }
                else if (v > v2) v2 = v;
            }
        #pragma unroll
        for (int off = 16; off < 64; off <<= 1) {      // reduce over quad (rows)
            float ov1 = __shfl_xor(v1, off, 64);
            int   oi1 = __shfl_xor(i1, off, 64);
            float ov2 = __shfl_xor(v2, off, 64);
            if (ov1 > v1 || (ov1 == v1 && oi1 < i1)) { v2 = fmaxf(v1, ov2); v1 = ov1; i1 = oi1; }
            else v2 = fmaxf(v2, ov1);
        }
        if (quad == 0) {
            int col = wn * 64 + ct * 16 + l15;
            sv1[wm * 256 + col] = v1; si1[wm * 256 + col] = i1; sv2[wm * 256 + col] = v2;
        }
    }
    __syncthreads();
    if (tid < 256) {
        int col = tid;
        float v1 = sv1[col]; int i1 = si1[col]; float v2 = sv2[col];
        #pragma unroll
        for (int m = 1; m < 4; ++m) {                  // ascending wm = ascending rows
            float ov1 = sv1[m * 256 + col]; int oi1 = si1[m * 256 + col]; float ov2 = sv2[m * 256 + col];
            if (ov1 > v1) { v2 = fmaxf(v1, ov2); v1 = ov1; i1 = oi1; }
            else v2 = fmaxf(v2, ov1);
        }
        size_t o = ((size_t)(b * NRT2 + rt)) * LP + c0 + col;
        pv1[o] = v1; pi1[o] = i1; pv2[o] = v2;
    }
}

// --------------------------------------------------------- merge kernel ----
// R16: thread = col, loop rc -> coalesced (lanes read contiguous 256-col
// runs of pv[rc]); each pv element read exactly once. Ascending-rc strict->
// first-wins (exact semantics as before). Writes final S (int+float); cols
// with approx top-2 gap < tau' = 0.5*bns appended to global flag list.
__global__ __launch_bounds__(256) void k_merge(
        const float* __restrict__ pv1, const int* __restrict__ pi1,
        const float* __restrict__ pv2, const float* __restrict__ bns,
        int* __restrict__ Sint, float* __restrict__ Sout,
        int* __restrict__ flaglist, int* __restrict__ nflag) {
    int b = blockIdx.y;
    int col = blockIdx.x * 256 + threadIdx.x;
    int gid = b * LP + col;
    float v1 = -FLT_MAX, v2 = -FLT_MAX; int i1 = 0;
    for (int rc = 0; rc < NRT2; ++rc) {                // ascending: first-wins
        size_t o = ((size_t)(b * NRT2 + rc)) * LP + col;
        float cv1 = pv1[o]; int ci1 = pi1[o]; float cv2 = pv2[o];
        if (cv1 > v1) { v2 = fmaxf(v1, cv2); v1 = cv1; i1 = ci1; }
        else v2 = fmaxf(v2, cv1);
    }
    Sint[gid] = i1;
    Sout[gid] = (float)i1;
    float tau = bns[gid] * 0.5f;                       // tau' = 0.5*bns
    if (v1 - v2 < tau) {
        int k = atomicAdd(nflag, 1);
        flaglist[k] = gid;
    }
}

// ----------------------------------------------------------- fix kernel ----
// R16: grid-stride over compact flag list; one block per flagged col.
// Body = R15 Phase B verbatim: exact fp32 argmax over pruned tiles
// (prune margin tau'), first-index tie-break. Overwrites Sint/Sout.
__global__ __launch_bounds__(256) void k_fix(
        const float* __restrict__ refimg, const float* __restrict__ lrimg,
        const float* __restrict__ rinv, const float* __restrict__ pv1,
        const float* __restrict__ bns,
        const int* __restrict__ flaglist, const int* __restrict__ nflag,
        int* __restrict__ Sint, float* __restrict__ Sout) {
    __shared__ float bcol[KF];
    __shared__ float spv[NRT2];
    __shared__ float red[4]; __shared__ int redi[4];
    int tid = threadIdx.x;
    int nf = *nflag;
    for (int fi = blockIdx.x; fi < nf; fi += gridDim.x) {
        int gid = flaglist[fi];
        int b = gid / LP, col = gid - b * LP;
        int lh = col / 96, lw = col - lh * 96;
        __syncthreads();                               // protect bcol/spv reuse
        if (tid < KF) {
            int c = tid / 9, r = tid - c * 9;
            int dy = r / 3, dx = r - dy * 3;
            int y = lh + dy - 1, x = lw + dx - 1;
            float v = 0.f;
            if ((unsigned)y < (unsigned)HH && (unsigned)x < (unsigned)WW)
                v = lrimg[((size_t)(b * CCH + c) * HH + y) * WW + x];
            bcol[tid] = v;
        }
        if (tid < NRT2) spv[tid] = pv1[((size_t)(b * NRT2 + tid)) * LP + col];
        __syncthreads();
        float v1 = -FLT_MAX;
        for (int rc = 0; rc < NRT2; ++rc) v1 = fmaxf(v1, spv[rc]);
        float thresh = v1 - bns[gid] * 0.5f;           // same tau' margin
        float best = -FLT_MAX; int bi = 0x7fffffff;
        for (int rc = 0; rc < NRT2; ++rc) {            // ascending rows
            if (spv[rc] < thresh) continue;            // prune (uniform)
            int row = rc * 256 + tid;
            int py = row / WW, px = row - py * WW;
            float s = 0.f;
            for (int c = 0; c < CCH; ++c) {
                const float* ic = refimg + (size_t)(b * CCH + c) * HH * WW;
                #pragma unroll
                for (int dy = 0; dy < 3; ++dy) {
                    int y = py + dy - 1;
                    if ((unsigned)y >= (unsigned)HH) continue;
                    #pragma unroll
                    for (int dx = 0; dx < 3; ++dx) {
                        int x = px + dx - 1;
                        if ((unsigned)x >= (unsigned)WW) continue;
                        s = fmaf(ic[y * WW + x], bcol[c * 9 + dy * 3 + dx], s);
                    }
                }
            }
            s *= rinv[b * LP + row];
            if (s > best || (s == best && row < bi)) { best = s; bi = row; }
        }
        #pragma unroll
        for (int off = 1; off < 64; off <<= 1) {
            float ov = __shfl_xor(best, off, 64);
            int   oi = __shfl_xor(bi, off, 64);
            if (ov > best || (ov == best && oi < bi)) { best = ov; bi = oi; }
        }
        if ((tid & 63) == 0) { red[tid >> 6] = best; redi[tid >> 6] = bi; }
        __syncthreads();
        if (tid == 0) {
            float b0 = red[0]; int i0 = redi[0];
            for (int k = 1; k < 4; ++k)
                if (red[k] > b0 || (red[k] == b0 && redi[k] < i0)) { b0 = red[k]; i0 = redi[k]; }
            Sint[gid] = i0;
            Sout[gid] = (float)i0;
        }
    }
}

// ---------------------------------------------------------- fold kernel ----
// R16: pure fold from final S. 8x8 pixel tiles, dim3(24,24,2); wave w =
// channels 4w..4w+3, lane = pixel (R13/R15 Phase C unchanged, S from Sint).
__global__ __launch_bounds__(256) void k_fold(
        const int* __restrict__ Sint, const float* __restrict__ org,
        float* __restrict__ outT) {
    __shared__ int s_S[6][6];
    int tx = blockIdx.x, ty = blockIdx.y, b = blockIdx.z;
    int x0 = tx * 8, y0 = ty * 8;
    int lhb = 4 * ty - 1; if (lhb < 0) lhb = 0;
    int lwb = 4 * tx - 1; if (lwb < 0) lwb = 0;
    int lhe = 4 * ty + 4; if (lhe > 95) lhe = 95;
    int lwe = 4 * tx + 4; if (lwe > 95) lwe = 95;
    int tid = threadIdx.x;

    if (tid < 36) {
        int ph = tid / 6, pw = tid - ph * 6;
        int lh = lhb + ph, lw = lwb + pw;
        s_S[ph][pw] = (lh <= lhe && lw <= lwe) ? Sint[b * LP + lh * 96 + lw] : 0;
    }
    __syncthreads();

    int wid = tid >> 6, pix = tid & 63;
    int pyL = pix >> 3, pxL = pix & 7;
    int y = y0 + pyL, x = x0 + pxL;
    const float* orgb = org + ((size_t)b * CCH + wid * 4) * OH * OW;
    float acc[4];
    #pragma unroll
    for (int c = 0; c < 4; ++c) acc[c] = 0.f;
    int lhm = (y + 2) >> 1;
    int lwm = (x + 2) >> 1;
    int lh0 = lhm - 2 > 0 ? lhm - 2 : 0;
    int lh1 = lhm < 95 ? lhm : 95;
    int lw0 = lwm - 2 > 0 ? lwm - 2 : 0;
    int lw1 = lwm < 95 ? lwm : 95;
    for (int lh = lh0; lh <= lh1; ++lh) {
        int dy = y + 2 - 2 * lh;
        if (dy > 5) continue;
        for (int lw = lw0; lw <= lw1; ++lw) {
            int dx = x + 2 - 2 * lw;
            if (dx > 5) continue;
            int s  = s_S[lh - lhb][lw - lwb];
            int sh = s / 96, sw = s - sh * 96;
            int u = 2 * sh + dy - 2;
            int v = 2 * sw + dx - 2;
            if ((unsigned)u < (unsigned)OH && (unsigned)v < (unsigned)OW) {
                const float* p = orgb + u * OW + v;
                #pragma unroll
                for (int c = 0; c < 4; ++c) acc[c] += p[(size_t)c * OH * OW];
            }
        }
    }
    #pragma unroll
    for (int c = 0; c < 4; ++c)
        outT[(((size_t)(b * CCH + wid * 4 + c)) * OH + y) * OW + x] = acc[c];
}

// --------------------------------------------------------------- launch ----
extern "C" void kernel_launch(void* const* d_in, const int* in_sizes, int n_in,
                              void* d_out, int out_size, void* d_ws, size_t ws_size,
                              hipStream_t stream) {
    const float* lrsr  = (const float*)d_in[0];
    const float* refsr = (const float*)d_in[1];
    const float* org   = (const float*)d_in[2];

    char* ws = (char*)d_ws;
    size_t o = 0;
    float* rinv     = (float*)(ws + o); o += (size_t)BATCH * LP * 4;
    float* bns      = (float*)(ws + o); o += (size_t)BATCH * LP * 4;
    float* pv1      = (float*)(ws + o); o += (size_t)BATCH * NRT2 * LP * 4;
    int*   pi1      = (int*)  (ws + o); o += (size_t)BATCH * NRT2 * LP * 4;
    float* pv2      = (float*)(ws + o); o += (size_t)BATCH * NRT2 * LP * 4;
    f16*   Abig     = (f16*)  (ws + o); o += (size_t)BATCH * LP * K3 * 2;
    f16*   Bbig     = (f16*)  (ws + o); o += (size_t)BATCH * LP * K3 * 2;
    int*   Sint     = (int*)  (ws + o); o += (size_t)BATCH * LP * 4;
    int*   flaglist = (int*)  (ws + o); o += (size_t)BATCH * LP * 4;
    int*   nflag    = (int*)  (ws + o); o += 16;

    float* outT = (float*)d_out;                          // 2*16*192*192
    float* outS = outT + (size_t)BATCH * CCH * OH * OW;   // 2*9216 as f32

    hipMemsetAsync(nflag, 0, 4, stream);
    k_pack2<<<dim3(96, BATCH, 8), 256, 0, stream>>>(refsr, lrsr, rinv, bns, Abig, Bbig);
    k_mfma<<<dim3(NCB2 * NRT2 * BATCH), 1024, 0, stream>>>(Abig, Bbig, pv1, pi1, pv2);
    k_merge<<<dim3(LP / 256, BATCH), 256, 0, stream>>>(pv1, pi1, pv2, bns,
                                                       Sint, outS, flaglist, nflag);
    k_fix<<<dim3(768), 256, 0, stream>>>(refsr, lrsr, rinv, pv1, bns,
                                         flaglist, nflag, Sint, outS);
    k_fold<<<dim3(24, 24, BATCH), 256, 0, stream>>>(Sint, org, outT);
}

// Round 7
// 292.854 us; speedup vs baseline: 1.5939x; 1.0110x over previous
//
#include <hip/hip_runtime.h>
#include <float.h>

// SearchTransfer MI355X — R17. k_mfma/k_merge/k_fix unchanged from R16
// (k_mfma 122us, byte-model confirmed). Tail fixes:
//  - k_pack2: norm phase parallelized 24->192 threads (8 partials/pixel x
//    2 channels, fixed-order reduce; ~1ulp norm shift << 15-sigma guard).
//  - k_fold: wave-uniform 36-patch loop (predicated lanes) -> same-patch
//    reads issue simultaneously across lanes, adjacent x -> adjacent v =>
//    coalesced 24-B runs instead of per-lane scattered dwords.
// B=2, C=16, H=W=96, k=3,pad=1,stride=1, lv=2. L=9216, KF=144.
// out = [T_org (2*16*192*192 f32), S (2*9216 as f32)]

#define BATCH 2
#define CCH   16
#define HH    96
#define WW    96
#define LP    9216
#define KF    144
#define K3    160      // 5 chunks x 32 k' (hi f16 only; k'>=144 zero-pad)
#define OH    192
#define OW    192
#define NRT2  36       // row tiles of 256
#define NCB2  36       // col blocks of 256

typedef _Float16 f16;
typedef __attribute__((ext_vector_type(8))) _Float16 f16x8;
typedef __attribute__((ext_vector_type(4))) float    f32x4;

__device__ __forceinline__ void async16(const void* g, void* l) {
    __builtin_amdgcn_global_load_lds(
        (const __attribute__((address_space(1))) void*)g,
        (__attribute__((address_space(3))) void*)l, 16, 0, 0);
}

// ---------------------------------------------------- fused norm + pack ----
// R17: norm phase parallelized. Phase N1: 192 threads (pxl, part) each sum
// 2 channels x 9 taps; Phase N2: 24 threads reduce 8 partials in fixed
// ascending order (deterministic).
__global__ __launch_bounds__(256) void k_pack2(
        const float* __restrict__ ref, const float* __restrict__ lr,
        float* __restrict__ rinv, float* __restrict__ bns,
        f16* __restrict__ Abig, f16* __restrict__ Bbig) {
    __shared__ float imgS[CCH][3][26];   // x origin at global xi = q*24-1
    __shared__ float pnorm[24][8];
    __shared__ float scl[24];
    int py = blockIdx.x, b = blockIdx.y;
    int side = blockIdx.z >> 2, q = blockIdx.z & 3;
    int tid = threadIdx.x;
    const float* img = (side ? lr : ref) + (size_t)b * CCH * HH * WW;

    for (int i = tid; i < CCH * 3 * 26; i += 256) {
        int c = i / 78, rem = i - c * 78;
        int rr = rem / 26, xx = rem - rr * 26;
        int y = py + rr - 1, xi = q * 24 - 1 + xx;
        float v = 0.f;
        if ((unsigned)y < (unsigned)HH && (unsigned)xi < (unsigned)WW)
            v = img[(c * HH + y) * WW + xi];
        imgS[c][rr][xx] = v;
    }
    __syncthreads();

    if (tid < 192) {                     // N1: partial norms
        int pxl = tid >> 3, part = tid & 7;
        float s = 0.f;
        #pragma unroll
        for (int cc = 0; cc < 2; ++cc) {
            int c = part * 2 + cc;
            #pragma unroll
            for (int dy = 0; dy < 3; ++dy)
                #pragma unroll
                for (int dx = 0; dx < 3; ++dx) {
                    float v = imgS[c][dy][pxl + dx];   // 0 when OOB: exact
                    s += v * v;
                }
        }
        pnorm[pxl][part] = s;
    }
    __syncthreads();

    if (tid < 24) {                      // N2: deterministic reduce
        int pxl = tid;
        float s = 0.f;
        #pragma unroll
        for (int p = 0; p < 8; ++p) s += pnorm[pxl][p];
        int gl = b * LP + py * 96 + q * 24 + pxl;
        if (side) { bns[gl] = 1024.0f * sqrtf(s); scl[pxl] = 1024.0f; }
        else { float r = 1.0f / fmaxf(sqrtf(s), 1e-12f); rinv[gl] = r; scl[pxl] = 1024.0f * r; }
    }
    __syncthreads();

    f16* dstb = (side ? Bbig : Abig) + (size_t)(b * LP + py * 96 + q * 24) * K3;
    for (int i = tid; i < 24 * 20; i += 256) {          // 20 granules/row
        int pxl = i / 20, g = i - pxl * 20;
        int f0 = g * 8;
        float sc = scl[pxl];
        f16x8 o;
        #pragma unroll
        for (int e = 0; e < 8; ++e) {
            int f = f0 + e;                             // 0..159 (>=144 pad)
            float v = 0.f;
            if (f < KF) {
                int c = f / 9, r9 = f - c * 9;
                int dy = r9 / 3, dx = r9 - dy * 3;
                v = imgS[c][dy][pxl + dx] * sc;
            }
            o[e] = (f16)v;
        }
        *(f16x8*)(dstb + (size_t)pxl * K3 + g * 8) = o;
    }
}

// -------------------------------------------------- MFMA GEMM + top-2 ------
// UNCHANGED from R16 (122us). Single-term, chunk = 32 k' (64 B/row), R10
// sync skeleton, pre-swizzled DMA source, conflict-free ds_read_b128.
__global__ __launch_bounds__(1024) void k_mfma(
        const f16* __restrict__ Abig, const f16* __restrict__ Bbig,
        float* __restrict__ pv1, int* __restrict__ pi1, float* __restrict__ pv2) {
    __shared__ f16 smem[2][256 * 64];                  // 2 x 32 KB
    int tid = threadIdx.x, lane = tid & 63, w = tid >> 6;   // w: 0..15
    int wm = w & 3, wn = w >> 2;
    int l15 = lane & 15, quad = lane >> 4;

    int i = blockIdx.x;                // 0..2591
    int xcd = i & 7, slot = i >> 3;    // slot 0..323
    int cb = slot / 9;                 // col tile 0..35 (major)
    int brt = xcd * 9 + (slot - cb * 9);   // 0..71
    int b = brt / NRT2, rt = brt - b * NRT2;
    int r0 = rt * 256, c0 = cb * 256;

    int ri  = ((lane >> 3) << 1) | ((lane >> 2) & 1);
    int qsw = (lane & 3) ^ ((lane >> 3) & 3);
    const f16* gsrc[2];
    int ldsbyte[2];                    // wave-uniform byte offset in one buffer
    #pragma unroll
    for (int j = 0; j < 2; ++j) {
        int G = w * 2 + j;             // 0..31
        int row8 = G * 16 + ri;        // 0..511 (A rows then B rows)
        const f16* base = (row8 < 256)
            ? Abig + (size_t)(b * LP + r0 + row8) * K3
            : Bbig + (size_t)(b * LP + c0 + (row8 - 256)) * K3;
        gsrc[j] = base + qsw * 8;
        ldsbyte[j] = G * 1024;         // 16 rows * 64 B
    }
    int l2 = l15 >> 1, lo1 = l15 & 1;
    int gsel = (quad ^ (l2 & 3)) * 16;
    int abyte[4], bbyte[4];
    #pragma unroll
    for (int t = 0; t < 4; ++t) {
        abyte[t] = (wm * 32 + t * 8 + l2) * 128 + lo1 * 64 + gsel;
        bbyte[t] = (128 + wn * 32 + t * 8 + l2) * 128 + lo1 * 64 + gsel;
    }

    f32x4 acc[4][4];
    #pragma unroll
    for (int ii = 0; ii < 4; ++ii)
        #pragma unroll
        for (int j = 0; j < 4; ++j) { acc[ii][j][0]=0.f; acc[ii][j][1]=0.f; acc[ii][j][2]=0.f; acc[ii][j][3]=0.f; }

    // prologue: chunk 0 -> buf 0
    #pragma unroll
    for (int j = 0; j < 2; ++j) async16(gsrc[j], (char*)smem[0] + ldsbyte[j]);

    for (int ch = 0; ch < 5; ++ch) {
        __syncthreads();               // drains own DMA; buf[ch&1] ready
        if (ch < 4) {
            #pragma unroll
            for (int j = 0; j < 2; ++j)
                async16(gsrc[j] + (ch + 1) * 32, (char*)smem[(ch + 1) & 1] + ldsbyte[j]);
        }
        const char* buf = (const char*)smem[ch & 1];
        f16x8 af[4], bf[4];
        #pragma unroll
        for (int t = 0; t < 4; ++t) af[t] = *(const f16x8*)(buf + abyte[t]);
        #pragma unroll
        for (int t = 0; t < 4; ++t) bf[t] = *(const f16x8*)(buf + bbyte[t]);
        #pragma unroll
        for (int rtt = 0; rtt < 4; ++rtt)
            #pragma unroll
            for (int ct = 0; ct < 4; ++ct)
                acc[rtt][ct] = __builtin_amdgcn_mfma_f32_16x16x32_f16(af[rtt], bf[ct], acc[rtt][ct], 0, 0, 0);
    }
    __syncthreads();                   // smem reads done -> overlay epilogue scratch

    float* sv1 = (float*)smem;                         // [4][256]
    int*   si1 = (int*)  ((char*)smem + 4096);
    float* sv2 = (float*)((char*)smem + 8192);

    int rbase = r0 + wm * 64 + (quad << 2);
    #pragma unroll
    for (int ct = 0; ct < 4; ++ct) {
        float v1 = -FLT_MAX, v2 = -FLT_MAX; int i1 = 0;
        #pragma unroll
        for (int rtt = 0; rtt < 4; ++rtt)
            #pragma unroll
            for (int e = 0; e < 4; ++e) {              // ascending rows; strict > = first wins
                float v = acc[rtt][ct][e];
                int rg = rbase + rtt * 16 + e;
                if (v > v1) { v2 = v1; v1 = v; i1 = rg; }
                else if (v > v2) v2 = v;
            }
        #pragma unroll
        for (int off = 16; off < 64; off <<= 1) {      // reduce over quad (rows)
            float ov1 = __shfl_xor(v1, off, 64);
            int   oi1 = __shfl_xor(i1, off, 64);
            float ov2 = __shfl_xor(v2, off, 64);
            if (ov1 > v1 || (ov1 == v1 && oi1 < i1)) { v2 = fmaxf(v1, ov2); v1 = ov1; i1 = oi1; }
            else v2 = fmaxf(v2, ov1);
        }
        if (quad == 0) {
            int col = wn * 64 + ct * 16 + l15;
            sv1[wm * 256 + col] = v1; si1[wm * 256 + col] = i1; sv2[wm * 256 + col] = v2;
        }
    }
    __syncthreads();
    if (tid < 256) {
        int col = tid;
        float v1 = sv1[col]; int i1 = si1[col]; float v2 = sv2[col];
        #pragma unroll
        for (int m = 1; m < 4; ++m) {                  // ascending wm = ascending rows
            float ov1 = sv1[m * 256 + col]; int oi1 = si1[m * 256 + col]; float ov2 = sv2[m * 256 + col];
            if (ov1 > v1) { v2 = fmaxf(v1, ov2); v1 = ov1; i1 = oi1; }
            else v2 = fmaxf(v2, ov1);
        }
        size_t o = ((size_t)(b * NRT2 + rt)) * LP + c0 + col;
        pv1[o] = v1; pi1[o] = i1; pv2[o] = v2;
    }
}

// --------------------------------------------------------- merge kernel ----
// UNCHANGED from R16. Coalesced col-parallel merge; compact flag list.
__global__ __launch_bounds__(256) void k_merge(
        const float* __restrict__ pv1, const int* __restrict__ pi1,
        const float* __restrict__ pv2, const float* __restrict__ bns,
        int* __restrict__ Sint, float* __restrict__ Sout,
        int* __restrict__ flaglist, int* __restrict__ nflag) {
    int b = blockIdx.y;
    int col = blockIdx.x * 256 + threadIdx.x;
    int gid = b * LP + col;
    float v1 = -FLT_MAX, v2 = -FLT_MAX; int i1 = 0;
    for (int rc = 0; rc < NRT2; ++rc) {                // ascending: first-wins
        size_t o = ((size_t)(b * NRT2 + rc)) * LP + col;
        float cv1 = pv1[o]; int ci1 = pi1[o]; float cv2 = pv2[o];
        if (cv1 > v1) { v2 = fmaxf(v1, cv2); v1 = cv1; i1 = ci1; }
        else v2 = fmaxf(v2, cv1);
    }
    Sint[gid] = i1;
    Sout[gid] = (float)i1;
    float tau = bns[gid] * 0.5f;                       // tau' = 0.5*bns
    if (v1 - v2 < tau) {
        int k = atomicAdd(nflag, 1);
        flaglist[k] = gid;
    }
}

// ----------------------------------------------------------- fix kernel ----
// UNCHANGED from R16. Grid-stride over flag list; exact fp32 argmax.
__global__ __launch_bounds__(256) void k_fix(
        const float* __restrict__ refimg, const float* __restrict__ lrimg,
        const float* __restrict__ rinv, const float* __restrict__ pv1,
        const float* __restrict__ bns,
        const int* __restrict__ flaglist, const int* __restrict__ nflag,
        int* __restrict__ Sint, float* __restrict__ Sout) {
    __shared__ float bcol[KF];
    __shared__ float spv[NRT2];
    __shared__ float red[4]; __shared__ int redi[4];
    int tid = threadIdx.x;
    int nf = *nflag;
    for (int fi = blockIdx.x; fi < nf; fi += gridDim.x) {
        int gid = flaglist[fi];
        int b = gid / LP, col = gid - b * LP;
        int lh = col / 96, lw = col - lh * 96;
        __syncthreads();                               // protect bcol/spv reuse
        if (tid < KF) {
            int c = tid / 9, r = tid - c * 9;
            int dy = r / 3, dx = r - dy * 3;
            int y = lh + dy - 1, x = lw + dx - 1;
            float v = 0.f;
            if ((unsigned)y < (unsigned)HH && (unsigned)x < (unsigned)WW)
                v = lrimg[((size_t)(b * CCH + c) * HH + y) * WW + x];
            bcol[tid] = v;
        }
        if (tid < NRT2) spv[tid] = pv1[((size_t)(b * NRT2 + tid)) * LP + col];
        __syncthreads();
        float v1 = -FLT_MAX;
        for (int rc = 0; rc < NRT2; ++rc) v1 = fmaxf(v1, spv[rc]);
        float thresh = v1 - bns[gid] * 0.5f;           // same tau' margin
        float best = -FLT_MAX; int bi = 0x7fffffff;
        for (int rc = 0; rc < NRT2; ++rc) {            // ascending rows
            if (spv[rc] < thresh) continue;            // prune (uniform)
            int row = rc * 256 + tid;
            int py = row / WW, px = row - py * WW;
            float s = 0.f;
            for (int c = 0; c < CCH; ++c) {
                const float* ic = refimg + (size_t)(b * CCH + c) * HH * WW;
                #pragma unroll
                for (int dy = 0; dy < 3; ++dy) {
                    int y = py + dy - 1;
                    if ((unsigned)y >= (unsigned)HH) continue;
                    #pragma unroll
                    for (int dx = 0; dx < 3; ++dx) {
                        int x = px + dx - 1;
                        if ((unsigned)x >= (unsigned)WW) continue;
                        s = fmaf(ic[y * WW + x], bcol[c * 9 + dy * 3 + dx], s);
                    }
                }
            }
            s *= rinv[b * LP + row];
            if (s > best || (s == best && row < bi)) { best = s; bi = row; }
        }
        #pragma unroll
        for (int off = 1; off < 64; off <<= 1) {
            float ov = __shfl_xor(best, off, 64);
            int   oi = __shfl_xor(bi, off, 64);
            if (ov > best || (ov == best && oi < bi)) { best = ov; bi = oi; }
        }
        if ((tid & 63) == 0) { red[tid >> 6] = best; redi[tid >> 6] = bi; }
        __syncthreads();
        if (tid == 0) {
            float b0 = red[0]; int i0 = redi[0];
            for (int k = 1; k < 4; ++k)
                if (red[k] > b0 || (red[k] == b0 && redi[k] < i0)) { b0 = red[k]; i0 = redi[k]; }
            Sint[gid] = i0;
            Sout[gid] = (float)i0;
        }
    }
}

// ---------------------------------------------------------- fold kernel ----
// R17: wave-uniform patch loop. All lanes iterate the block's 6x6 patch
// window together (uniform s -> broadcast); lanes predicated by dy,dx in
// [0,6). Same contribution set as the per-lane loop (pixel y contributes to
// lh in [(y-2)>>1,(y+2)>>1], a subset of the window); adjacent lanes read
// adjacent v -> coalesced 24-B runs.
__global__ __launch_bounds__(256) void k_fold(
        const int* __restrict__ Sint, const float* __restrict__ org,
        float* __restrict__ outT) {
    __shared__ int s_S[6][6];
    int tx = blockIdx.x, ty = blockIdx.y, b = blockIdx.z;
    int x0 = tx * 8, y0 = ty * 8;
    int lhb = 4 * ty - 1; if (lhb < 0) lhb = 0;
    int lwb = 4 * tx - 1; if (lwb < 0) lwb = 0;
    int lhe = 4 * ty + 4; if (lhe > 95) lhe = 95;
    int lwe = 4 * tx + 4; if (lwe > 95) lwe = 95;
    int nh = lhe - lhb + 1, nw = lwe - lwb + 1;        // 5 or 6
    int tid = threadIdx.x;

    if (tid < 36) {
        int ph = tid / 6, pw = tid - ph * 6;
        int lh = lhb + ph, lw = lwb + pw;
        s_S[ph][pw] = (lh <= lhe && lw <= lwe) ? Sint[b * LP + lh * 96 + lw] : 0;
    }
    __syncthreads();

    int wid = tid >> 6, pix = tid & 63;
    int pyL = pix >> 3, pxL = pix & 7;
    int y = y0 + pyL, x = x0 + pxL;
    const float* orgb = org + ((size_t)b * CCH + wid * 4) * OH * OW;
    float acc[4];
    #pragma unroll
    for (int c = 0; c < 4; ++c) acc[c] = 0.f;
    for (int ph = 0; ph < nh; ++ph) {                  // wave-uniform loop
        int lh = lhb + ph;
        int dy = y + 2 - 2 * lh;                       // per lane
        for (int pw = 0; pw < nw; ++pw) {
            int lw = lwb + pw;
            int dx = x + 2 - 2 * lw;
            int s  = s_S[ph][pw];                      // uniform -> broadcast
            int sh = s / 96, sw = s - sh * 96;
            if ((unsigned)dy < 6u && (unsigned)dx < 6u) {
                int u = 2 * sh + dy - 2;
                int v = 2 * sw + dx - 2;
                if ((unsigned)u < (unsigned)OH && (unsigned)v < (unsigned)OW) {
                    const float* p = orgb + u * OW + v;
                    #pragma unroll
                    for (int c = 0; c < 4; ++c) acc[c] += p[(size_t)c * OH * OW];
                }
            }
        }
    }
    #pragma unroll
    for (int c = 0; c < 4; ++c)
        outT[(((size_t)(b * CCH + wid * 4 + c)) * OH + y) * OW + x] = acc[c];
}

// --------------------------------------------------------------- launch ----
extern "C" void kernel_launch(void* const* d_in, const int* in_sizes, int n_in,
                              void* d_out, int out_size, void* d_ws, size_t ws_size,
                              hipStream_t stream) {
    const float* lrsr  = (const float*)d_in[0];
    const float* refsr = (const float*)d_in[1];
    const float* org   = (const float*)d_in[2];

    char* ws = (char*)d_ws;
    size_t o = 0;
    float* rinv     = (float*)(ws + o); o += (size_t)BATCH * LP * 4;
    float* bns      = (float*)(ws + o); o += (size_t)BATCH * LP * 4;
    float* pv1      = (float*)(ws + o); o += (size_t)BATCH * NRT2 * LP * 4;
    int*   pi1      = (int*)  (ws + o); o += (size_t)BATCH * NRT2 * LP * 4;
    float* pv2      = (float*)(ws + o); o += (size_t)BATCH * NRT2 * LP * 4;
    f16*   Abig     = (f16*)  (ws + o); o += (size_t)BATCH * LP * K3 * 2;
    f16*   Bbig     = (f16*)  (ws + o); o += (size_t)BATCH * LP * K3 * 2;
    int*   Sint     = (int*)  (ws + o); o += (size_t)BATCH * LP * 4;
    int*   flaglist = (int*)  (ws + o); o += (size_t)BATCH * LP * 4;
    int*   nflag    = (int*)  (ws + o); o += 16;

    float* outT = (float*)d_out;                          // 2*16*192*192
    float* outS = outT + (size_t)BATCH * CCH * OH * OW;   // 2*9216 as f32

    hipMemsetAsync(nflag, 0, 4, stream);
    k_pack2<<<dim3(96, BATCH, 8), 256, 0, stream>>>(refsr, lrsr, rinv, bns, Abig, Bbig);
    k_mfma<<<dim3(NCB2 * NRT2 * BATCH), 1024, 0, stream>>>(Abig, Bbig, pv1, pi1, pv2);
    k_merge<<<dim3(LP / 256, BATCH), 256, 0, stream>>>(pv1, pi1, pv2, bns,
                                                       Sint, outS, flaglist, nflag);
    k_fix<<<dim3(768), 256, 0, stream>>>(refsr, lrsr, rinv, pv1, bns,
                                         flaglist, nflag, Sint, outS);
    k_fold<<<dim3(24, 24, BATCH), 256, 0, stream>>>(Sint, org, outT);
}